// Round 5
// baseline (197.330 us; speedup 1.0000x reference)
//
#include <hip/hip_runtime.h>
#include <hip/hip_cooperative_groups.h>

namespace cg = cooperative_groups;

// Segment-sum via gather (round 5): single cooperative kernel.
// r1 scatter-atomics 449us -> r2 hist+gather 43.3us -> r3 NT-hints 49.7us
// (REVERTED) -> r4 reg-prefetched slots 42.7us.
// r5: fuse {zero counts, hist, gather} into one cooperative launch with two
// grid.sync()s -- removes 2 dispatch boundaries + memset dispatch from the
// graph. Roofline ~31us at 6.3 TB/s for the mandatory 194MiB.

#define CAP 32          // slot capacity per segment; Poisson(2) tail beyond 32 ~ 1e-26
#define N_SEG 16384
#define DDIM 1024
#define GRID 1024       // 4 blocks/CU -> guaranteed co-resident for cooperative
#define BLOCK 256

typedef __attribute__((ext_vector_type(4))) float f4;
typedef __attribute__((ext_vector_type(4))) int i4;

__device__ __forceinline__ f4 gather_segment(const float* __restrict__ data,
                                             const int* __restrict__ tags,
                                             const unsigned short* __restrict__ slots,
                                             int s, int k, int col, int n_rows) {
    f4 acc = {0.f, 0.f, 0.f, 0.f};
    if (k <= CAP) {
        // Slot list: 32 u16 = 64B = 4 i4 words, 8 ids/word, prefetched to regs
        // so the up-to-8 data loads per word issue independently.
        const i4* sp = reinterpret_cast<const i4*>(slots + (long)s * CAP);
        int done = 0;
        #pragma unroll
        for (int w = 0; w < 4; ++w) {
            if (done >= k) break;                   // wave-uniform
            i4 word = sp[w];
            #pragma unroll
            for (int e = 0; e < 4; ++e) {
                int pair = word[e];
                int r0 = pair & 0xFFFF;
                int r1 = (pair >> 16) & 0xFFFF;
                if (done < k) {
                    acc += *reinterpret_cast<const f4*>(data + (long)r0 * DDIM + col);
                    ++done;
                }
                if (done < k) {
                    acc += *reinterpret_cast<const f4*>(data + (long)r1 * DDIM + col);
                    ++done;
                }
            }
        }
    } else {
        // Overflow fallback (deterministic, essentially never taken).
        for (int r = 0; r < n_rows; ++r) {
            if (tags[r] == s) {
                acc += *reinterpret_cast<const f4*>(data + (long)r * DDIM + col);
            }
        }
    }
    return acc;
}

__global__ void fused_combine(const float* __restrict__ data,
                              const int* __restrict__ tags,
                              int* __restrict__ counts,
                              unsigned short* __restrict__ slots,
                              float* __restrict__ out,
                              int n_rows) {
    cg::grid_group grid = cg::this_grid();
    int tid = blockIdx.x * blockDim.x + threadIdx.x;
    int nthreads = gridDim.x * blockDim.x;

    // Phase 0: zero the counts.
    for (int i = tid; i < N_SEG; i += nthreads) counts[i] = 0;
    grid.sync();

    // Phase 1: histogram + inverted index.
    for (int r = tid; r < n_rows; r += nthreads) {
        int t = tags[r];
        int pos = atomicAdd(&counts[t], 1);
        if (pos < CAP) slots[(long)t * CAP + pos] = (unsigned short)r;
    }
    grid.sync();

    // Phase 2: gather. Each block owns N_SEG/GRID segments; 256 threads x
    // float4 cover the 1024 columns.
    int col = threadIdx.x * 4;
    for (int s = blockIdx.x; s < N_SEG; s += gridDim.x) {
        int k = counts[s];
        f4 acc = gather_segment(data, tags, slots, s, k, col, n_rows);
        *reinterpret_cast<f4*>(out + (long)s * DDIM + col) = acc;
    }
}

// ---- fallback path (3 dispatches), used if cooperative launch is refused ----

__global__ void hist_fill(const int* __restrict__ tags, int n_rows,
                          int* __restrict__ counts,
                          unsigned short* __restrict__ slots) {
    int r = blockIdx.x * blockDim.x + threadIdx.x;
    if (r < n_rows) {
        int t = tags[r];
        int pos = atomicAdd(&counts[t], 1);
        if (pos < CAP) slots[(long)t * CAP + pos] = (unsigned short)r;
    }
}

__global__ void gather_sum(const float* __restrict__ data,
                           const int* __restrict__ tags,
                           const int* __restrict__ counts,
                           const unsigned short* __restrict__ slots,
                           float* __restrict__ out,
                           int n_rows) {
    int s = blockIdx.x;
    int col = threadIdx.x * 4;
    int k = counts[s];
    f4 acc = gather_segment(data, tags, slots, s, k, col, n_rows);
    *reinterpret_cast<f4*>(out + (long)s * DDIM + col) = acc;
}

__global__ void combine_scatter_add(const float* __restrict__ data,
                                    const int* __restrict__ tags,
                                    float* __restrict__ out,
                                    long total_elems) {
    long stride = (long)gridDim.x * blockDim.x * 4L;
    for (long i = ((long)blockIdx.x * blockDim.x + threadIdx.x) * 4L;
         i < total_elems; i += stride) {
        float4 v = *reinterpret_cast<const float4*>(data + i);
        long row = i >> 10;
        int col = (int)(i & 1023);
        int tag = tags[row];
        float* dst = out + ((long)tag << 10) + col;
        atomicAdd(dst + 0, v.x);
        atomicAdd(dst + 1, v.y);
        atomicAdd(dst + 2, v.z);
        atomicAdd(dst + 3, v.w);
    }
}

extern "C" void kernel_launch(void* const* d_in, const int* in_sizes, int n_in,
                              void* d_out, int out_size, void* d_ws, size_t ws_size,
                              hipStream_t stream) {
    const float* data = (const float*)d_in[0];
    const int* tags = (const int*)d_in[1];
    float* out = (float*)d_out;

    long total = (long)in_sizes[0];   // 33554432
    int n_rows = in_sizes[1];         // 32768

    size_t counts_bytes = (size_t)N_SEG * sizeof(int);                 // 64 KiB
    size_t slots_bytes = (size_t)N_SEG * CAP * sizeof(unsigned short); // 1 MiB
    size_t need = counts_bytes + slots_bytes;

    if (ws_size < need) {
        hipMemsetAsync(d_out, 0, (size_t)out_size * sizeof(float), stream);
        combine_scatter_add<<<2048, 256, 0, stream>>>(data, tags, out, total);
        return;
    }

    int* counts = (int*)d_ws;
    unsigned short* slots = (unsigned short*)((char*)d_ws + counts_bytes);

    void* args[] = {(void*)&data, (void*)&tags, (void*)&counts,
                    (void*)&slots, (void*)&out, (void*)&n_rows};
    hipError_t err = hipLaunchCooperativeKernel(
        reinterpret_cast<const void*>(&fused_combine),
        dim3(GRID), dim3(BLOCK), args, 0, stream);

    if (err != hipSuccess) {
        // Fallback: 3-dispatch pipeline (r4 behavior).
        hipMemsetAsync(counts, 0, counts_bytes, stream);
        hist_fill<<<(n_rows + 255) / 256, 256, 0, stream>>>(tags, n_rows, counts, slots);
        gather_sum<<<N_SEG, 256, 0, stream>>>(data, tags, counts, slots, out, n_rows);
    }
}

// Round 6
// 43.881 us; speedup vs baseline: 4.4969x; 4.4969x over previous
//
#include <hip/hip_runtime.h>

// Segment-sum via gather (round 6).
// History: r1 scatter-atomics 449us (L2-atomic-bound) -> r2 hist+gather 43.3us
// -> r3 NT-hints 49.7us REVERTED (data is L3-resident across replays; NT loads
// bypassed L3) -> r4 reg-prefetched slots 42.7us -> r5 fused cooperative 197us
// REVERTED (persistent blocks serialized dependent chains; 16384 independent
// blocks hide latency far better).
// r6: r4 structure + (a) counts and slot-word0 issued in parallel (3->2
// dependent latencies per block; k<=8 covers 99.98% of segments), (b) 2 blocks
// per segment (block=128 thr x 512 cols) -> 2x independent chains per CU.

#define CAP 32          // slot capacity per segment; Poisson(2) tail beyond 32 ~ 1e-26
#define DDIM 1024

typedef __attribute__((ext_vector_type(4))) float f4;
typedef __attribute__((ext_vector_type(4))) int i4;

__global__ void hist_fill(const int* __restrict__ tags, int n_rows,
                          int* __restrict__ counts,
                          unsigned short* __restrict__ slots) {
    int r = blockIdx.x * blockDim.x + threadIdx.x;
    if (r < n_rows) {
        int t = tags[r];
        int pos = atomicAdd(&counts[t], 1);
        if (pos < CAP) slots[(long)t * CAP + pos] = (unsigned short)r;
    }
}

// Accumulate up to 8 rows from one slot word (ids already in registers).
__device__ __forceinline__ void acc_word(const float* __restrict__ data,
                                         i4 word, int base, int k, int col,
                                         f4& acc) {
    #pragma unroll
    for (int e = 0; e < 4; ++e) {
        int pair = word[e];
        int r0 = pair & 0xFFFF;
        int r1 = (pair >> 16) & 0xFFFF;
        if (base + 2 * e < k)
            acc += *reinterpret_cast<const f4*>(data + (long)r0 * DDIM + col);
        if (base + 2 * e + 1 < k)
            acc += *reinterpret_cast<const f4*>(data + (long)r1 * DDIM + col);
    }
}

__global__ void gather_sum(const float* __restrict__ data,
                           const int* __restrict__ tags,
                           const int* __restrict__ counts,
                           const unsigned short* __restrict__ slots,
                           float* __restrict__ out,
                           int n_rows) {
    int b = blockIdx.x;
    int s = b >> 1;                       // segment id
    int col = ((b & 1) << 9) + threadIdx.x * 4;   // half*512 + tid*4, 128 thr

    const i4* sp = reinterpret_cast<const i4*>(slots + (long)s * CAP);
    // Issue both independent loads up front: count + first 8 slot ids.
    int k = counts[s];
    i4 w0 = sp[0];

    f4 acc = {0.f, 0.f, 0.f, 0.f};
    if (k <= 8) {                         // 99.98% of segments
        acc_word(data, w0, 0, k, col, acc);
    } else if (k <= CAP) {
        acc_word(data, w0, 0, k, col, acc);
        i4 w1 = sp[1], w2 = sp[2], w3 = sp[3];
        acc_word(data, w1, 8, k, col, acc);
        acc_word(data, w2, 16, k, col, acc);
        acc_word(data, w3, 24, k, col, acc);
    } else {
        // Overflow fallback (deterministic, essentially never taken).
        for (int r = 0; r < n_rows; ++r) {
            if (tags[r] == s) {
                acc += *reinterpret_cast<const f4*>(data + (long)r * DDIM + col);
            }
        }
    }
    *reinterpret_cast<f4*>(out + (long)s * DDIM + col) = acc;
}

// Safety-net scatter kernel (used only if ws_size is too small for the index).
__global__ void combine_scatter_add(const float* __restrict__ data,
                                    const int* __restrict__ tags,
                                    float* __restrict__ out,
                                    long total_elems) {
    long stride = (long)gridDim.x * blockDim.x * 4L;
    for (long i = ((long)blockIdx.x * blockDim.x + threadIdx.x) * 4L;
         i < total_elems; i += stride) {
        float4 v = *reinterpret_cast<const float4*>(data + i);
        long row = i >> 10;
        int col = (int)(i & 1023);
        int tag = tags[row];
        float* dst = out + ((long)tag << 10) + col;
        atomicAdd(dst + 0, v.x);
        atomicAdd(dst + 1, v.y);
        atomicAdd(dst + 2, v.z);
        atomicAdd(dst + 3, v.w);
    }
}

extern "C" void kernel_launch(void* const* d_in, const int* in_sizes, int n_in,
                              void* d_out, int out_size, void* d_ws, size_t ws_size,
                              hipStream_t stream) {
    const float* data = (const float*)d_in[0];
    const int* tags = (const int*)d_in[1];
    float* out = (float*)d_out;

    long total = (long)in_sizes[0];   // 33554432
    int n_rows = in_sizes[1];         // 32768
    int n_seg = out_size / DDIM;      // 16384

    size_t counts_bytes = (size_t)n_seg * sizeof(int);                 // 64 KiB
    size_t slots_bytes = (size_t)n_seg * CAP * sizeof(unsigned short); // 1 MiB
    size_t need = counts_bytes + slots_bytes;

    if (ws_size < need) {
        hipMemsetAsync(d_out, 0, (size_t)out_size * sizeof(float), stream);
        combine_scatter_add<<<2048, 256, 0, stream>>>(data, tags, out, total);
        return;
    }

    int* counts = (int*)d_ws;
    unsigned short* slots = (unsigned short*)((char*)d_ws + counts_bytes);

    hipMemsetAsync(counts, 0, counts_bytes, stream);

    hist_fill<<<(n_rows + 255) / 256, 256, 0, stream>>>(tags, n_rows, counts, slots);

    // 2 blocks per segment, 128 threads x float4 = 512 cols per block.
    gather_sum<<<n_seg * 2, 128, 0, stream>>>(data, tags, counts, slots, out, n_rows);
}

// Round 7
// 43.046 us; speedup vs baseline: 4.5841x; 1.0194x over previous
//
#include <hip/hip_runtime.h>

// Segment-sum via gather (round 7).
// History: r1 scatter-atomics 449us (L2-atomic-bound) -> r2 hist+gather 43.3us
// -> r3 NT on loads+stores 49.7us REVERTED (data reads are L3-served; NT loads
// bypassed L3) -> r4 reg-prefetched slots 42.7us BEST -> r5 fused cooperative
// 197us REVERTED -> r6 2-blocks/seg 43.9us NEUTRAL (BW-bound, not
// latency-bound).
// r7 = r4 + ONE change: nontemporal STORE on out (loads stay cached).
// Theory: out's 64MiB write-allocate evicts half of data from L3 each replay
// (r5 counters: 67MB HBM fetch steady-state). NT store keeps out out of
// L2/L3 -> data fully L3-resident -> HBM only carries the 64MiB write.

#define CAP 32          // slot capacity per segment; Poisson(2) tail beyond 32 ~ 1e-26
#define DDIM 1024

typedef __attribute__((ext_vector_type(4))) float f4;
typedef __attribute__((ext_vector_type(4))) int i4;

__global__ void hist_fill(const int* __restrict__ tags, int n_rows,
                          int* __restrict__ counts,
                          unsigned short* __restrict__ slots) {
    int r = blockIdx.x * blockDim.x + threadIdx.x;
    if (r < n_rows) {
        int t = tags[r];
        int pos = atomicAdd(&counts[t], 1);
        if (pos < CAP) slots[(long)t * CAP + pos] = (unsigned short)r;
    }
}

__global__ void gather_sum(const float* __restrict__ data,
                           const int* __restrict__ tags,
                           const int* __restrict__ counts,
                           const unsigned short* __restrict__ slots,
                           float* __restrict__ out,
                           int n_rows) {
    int s = blockIdx.x;                 // segment id, one block per output row
    int col = threadIdx.x * 4;          // 256 threads x float4 = 1024 cols
    int k = counts[s];
    f4 acc = {0.f, 0.f, 0.f, 0.f};

    if (k <= CAP) {
        // Slot list: 32 u16 = 64B = 4 i4 words, 8 ids/word, prefetched to regs
        // so the up-to-8 data loads per word issue independently.
        const i4* sp = reinterpret_cast<const i4*>(slots + (long)s * CAP);
        int done = 0;
        #pragma unroll
        for (int w = 0; w < 4; ++w) {
            if (done >= k) break;                   // wave-uniform
            i4 word = sp[w];
            #pragma unroll
            for (int e = 0; e < 4; ++e) {
                int pair = word[e];
                int r0 = pair & 0xFFFF;
                int r1 = (pair >> 16) & 0xFFFF;
                if (done < k) {
                    acc += *reinterpret_cast<const f4*>(data + (long)r0 * DDIM + col);
                    ++done;
                }
                if (done < k) {
                    acc += *reinterpret_cast<const f4*>(data + (long)r1 * DDIM + col);
                    ++done;
                }
            }
        }
    } else {
        // Overflow fallback (deterministic, essentially never taken): slots
        // hold an arbitrary subset, so recompute the whole segment by scanning
        // all tags (L2-resident broadcast reads).
        for (int r = 0; r < n_rows; ++r) {
            if (tags[r] == s) {
                acc += *reinterpret_cast<const f4*>(data + (long)r * DDIM + col);
            }
        }
    }
    // Out is written once, never re-read in-graph: stream past L2/L3 so the
    // data array stays L3-resident across replays.
    __builtin_nontemporal_store(acc, reinterpret_cast<f4*>(out + (long)s * DDIM + col));
}

// Safety-net scatter kernel (used only if ws_size is too small for the index).
__global__ void combine_scatter_add(const float* __restrict__ data,
                                    const int* __restrict__ tags,
                                    float* __restrict__ out,
                                    long total_elems) {
    long stride = (long)gridDim.x * blockDim.x * 4L;
    for (long i = ((long)blockIdx.x * blockDim.x + threadIdx.x) * 4L;
         i < total_elems; i += stride) {
        float4 v = *reinterpret_cast<const float4*>(data + i);
        long row = i >> 10;
        int col = (int)(i & 1023);
        int tag = tags[row];
        float* dst = out + ((long)tag << 10) + col;
        atomicAdd(dst + 0, v.x);
        atomicAdd(dst + 1, v.y);
        atomicAdd(dst + 2, v.z);
        atomicAdd(dst + 3, v.w);
    }
}

extern "C" void kernel_launch(void* const* d_in, const int* in_sizes, int n_in,
                              void* d_out, int out_size, void* d_ws, size_t ws_size,
                              hipStream_t stream) {
    const float* data = (const float*)d_in[0];
    const int* tags = (const int*)d_in[1];
    float* out = (float*)d_out;

    long total = (long)in_sizes[0];   // 33554432
    int n_rows = in_sizes[1];         // 32768
    int n_seg = out_size / DDIM;      // 16384

    size_t counts_bytes = (size_t)n_seg * sizeof(int);                 // 64 KiB
    size_t slots_bytes = (size_t)n_seg * CAP * sizeof(unsigned short); // 1 MiB
    size_t need = counts_bytes + slots_bytes;

    if (ws_size < need) {
        hipMemsetAsync(d_out, 0, (size_t)out_size * sizeof(float), stream);
        combine_scatter_add<<<2048, 256, 0, stream>>>(data, tags, out, total);
        return;
    }

    int* counts = (int*)d_ws;
    unsigned short* slots = (unsigned short*)((char*)d_ws + counts_bytes);

    hipMemsetAsync(counts, 0, counts_bytes, stream);

    hist_fill<<<(n_rows + 255) / 256, 256, 0, stream>>>(tags, n_rows, counts, slots);

    gather_sum<<<n_seg, 256, 0, stream>>>(data, tags, counts, slots, out, n_rows);
}